// Round 1
// baseline (21497.043 us; speedup 1.0000x reference)
//
#include <hip/hip_runtime.h>
#include <hip/hip_bf16.h>

#define Bb 8
#define Ss 128
#define Hh 1024
#define Ee 1024
#define Vv 32000
#define NROWS (Bb*Ss)   // 1024

// ---------------------------------------------------------------------------
// Generic rows x 1024 GEMM, K=1024.
// MODE 0: A-row = emb[labels[row]] (gather), epilogue relu      (input proj)
// MODE 1: A-row = A[row]           (direct), epilogue exact gelu (head dense)
// grid (4, 64), block 256. 16 rows x 256 cols per block, 4x4 per thread.
// ---------------------------------------------------------------------------
template<int MODE>
__global__ __launch_bounds__(256) void k_gemm1024(
    const int* __restrict__ labels, const float* __restrict__ A,
    const float* __restrict__ W, const float* __restrict__ bias,
    float* __restrict__ out)
{
    __shared__ float Als[16][32];
    const int tid  = threadIdx.x;
    const int jj   = (blockIdx.x << 8) + ((tid & 63) << 2);  // 4 cols
    const int rg   = tid >> 6;                                // row group 0..3
    const int row0 = blockIdx.y << 4;
    float acc[4][4] = {};
    for (int k0 = 0; k0 < Ee; k0 += 32) {
        __syncthreads();
        #pragma unroll
        for (int u = 0; u < 2; ++u) {
            int i = (u << 8) + tid;
            int r = i >> 5, kk = i & 31;
            int row = row0 + r;
            size_t base = (MODE == 0) ? (size_t)labels[row] * Ee : (size_t)row * Hh;
            Als[r][kk] = A[base + k0 + kk];
        }
        __syncthreads();
        #pragma unroll 8
        for (int kk = 0; kk < 32; ++kk) {
            const float4 w4 = *reinterpret_cast<const float4*>(&W[(size_t)(k0 + kk) * Hh + jj]);
            #pragma unroll
            for (int i = 0; i < 4; ++i) {
                float a = Als[(rg << 2) + i][kk];
                acc[i][0] = fmaf(a, w4.x, acc[i][0]);
                acc[i][1] = fmaf(a, w4.y, acc[i][1]);
                acc[i][2] = fmaf(a, w4.z, acc[i][2]);
                acc[i][3] = fmaf(a, w4.w, acc[i][3]);
            }
        }
    }
    const float4 b4 = *reinterpret_cast<const float4*>(&bias[jj]);
    #pragma unroll
    for (int i = 0; i < 4; ++i) {
        int row = row0 + (rg << 2) + i;
        float v[4] = {acc[i][0] + b4.x, acc[i][1] + b4.y, acc[i][2] + b4.z, acc[i][3] + b4.w};
        float o[4];
        #pragma unroll
        for (int j = 0; j < 4; ++j) {
            if (MODE == 0) o[j] = fmaxf(v[j], 0.f);
            else           o[j] = 0.5f * v[j] * (1.f + erff(v[j] * 0.70710678f));
        }
        *reinterpret_cast<float4*>(&out[(size_t)row * Hh + jj]) =
            make_float4(o[0], o[1], o[2], o[3]);
    }
}

// ---------------------------------------------------------------------------
// Scan step m: for rows t in [m+1, 127] (positions <= m are dead):
//   pre[b,t,:] = 0.1*relu([h[b,t-1,:], h[b,t,:]] @ W_sani + b_sani) + h[b,t,:]
// The comb row is the contiguous 2048-float window at h[b, t-1, 0].
// grid (4, ceil(nt/16), 8), block 256.
// ---------------------------------------------------------------------------
__global__ __launch_bounds__(256) void k_scan_gemm(
    const float* __restrict__ hsrc, const float* __restrict__ W,
    const float* __restrict__ bias, float* __restrict__ hdst, int m)
{
    __shared__ float Als[16][32];
    const int tid = threadIdx.x;
    const int jj  = (blockIdx.x << 8) + ((tid & 63) << 2);
    const int rg  = tid >> 6;
    const int b   = blockIdx.z;
    const int t0  = m + 1 + (blockIdx.y << 4);
    const float* hb = hsrc + (size_t)b * Ss * Hh;
    float acc[4][4] = {};
    for (int k0 = 0; k0 < 2 * Hh; k0 += 32) {
        __syncthreads();
        #pragma unroll
        for (int u = 0; u < 2; ++u) {
            int i = (u << 8) + tid;
            int r = i >> 5, kk = i & 31;
            int t = t0 + r; t = (t > Ss - 1) ? (Ss - 1) : t;   // clamp: discarded rows
            Als[r][kk] = hb[(size_t)(t - 1) * Hh + k0 + kk];
        }
        __syncthreads();
        #pragma unroll 8
        for (int kk = 0; kk < 32; ++kk) {
            const float4 w4 = *reinterpret_cast<const float4*>(&W[(size_t)(k0 + kk) * Hh + jj]);
            #pragma unroll
            for (int i = 0; i < 4; ++i) {
                float a = Als[(rg << 2) + i][kk];
                acc[i][0] = fmaf(a, w4.x, acc[i][0]);
                acc[i][1] = fmaf(a, w4.y, acc[i][1]);
                acc[i][2] = fmaf(a, w4.z, acc[i][2]);
                acc[i][3] = fmaf(a, w4.w, acc[i][3]);
            }
        }
    }
    const float4 b4 = *reinterpret_cast<const float4*>(&bias[jj]);
    #pragma unroll
    for (int i = 0; i < 4; ++i) {
        int t = t0 + (rg << 2) + i;
        if (t <= Ss - 1) {
            const float4 h4 = *reinterpret_cast<const float4*>(&hb[(size_t)t * Hh + jj]);
            float4 o;
            o.x = 0.1f * fmaxf(acc[i][0] + b4.x, 0.f) + h4.x;
            o.y = 0.1f * fmaxf(acc[i][1] + b4.y, 0.f) + h4.y;
            o.z = 0.1f * fmaxf(acc[i][2] + b4.z, 0.f) + h4.z;
            o.w = 0.1f * fmaxf(acc[i][3] + b4.w, 0.f) + h4.w;
            *reinterpret_cast<float4*>(&hdst[((size_t)b * Ss + t) * Hh + jj]) = o;
        }
    }
}

// ---------------------------------------------------------------------------
// LayerNorm (eps 1e-5) in place on hdst rows t in [m+1,127]; the t==m+1 row is
// this step's extracted output -> outState[b, m, :].  grid (nt, 8), block 256.
// ---------------------------------------------------------------------------
__global__ __launch_bounds__(256) void k_scan_ln(
    float* __restrict__ hdst, const float* __restrict__ g,
    const float* __restrict__ be, float* __restrict__ outState, int m)
{
    const int t = m + 1 + blockIdx.x;
    const int b = blockIdx.y;
    const int tid = threadIdx.x;
    float* rowp = hdst + ((size_t)b * Ss + t) * Hh;
    float4 v = *reinterpret_cast<float4*>(&rowp[tid << 2]);
    float s1 = v.x + v.y + v.z + v.w;
    float s2 = v.x*v.x + v.y*v.y + v.z*v.z + v.w*v.w;
    #pragma unroll
    for (int off = 1; off < 64; off <<= 1) { s1 += __shfl_xor(s1, off); s2 += __shfl_xor(s2, off); }
    __shared__ float r1[4], r2[4];
    if ((tid & 63) == 0) { r1[tid >> 6] = s1; r2[tid >> 6] = s2; }
    __syncthreads();
    s1 = r1[0] + r1[1] + r1[2] + r1[3];
    s2 = r2[0] + r2[1] + r2[2] + r2[3];
    const float mu = s1 * (1.f / Hh);
    const float rs = rsqrtf(s2 * (1.f / Hh) - mu * mu + 1e-5f);
    const float4 g4 = *reinterpret_cast<const float4*>(&g[tid << 2]);
    const float4 b4 = *reinterpret_cast<const float4*>(&be[tid << 2]);
    float4 o;
    o.x = (v.x - mu) * rs * g4.x + b4.x;
    o.y = (v.y - mu) * rs * g4.y + b4.y;
    o.z = (v.z - mu) * rs * g4.z + b4.z;
    o.w = (v.w - mu) * rs * g4.w + b4.w;
    *reinterpret_cast<float4*>(&rowp[tid << 2]) = o;
    if (t == m + 1)
        *reinterpret_cast<float4*>(&outState[((size_t)b * Ss + m) * Hh + (tid << 2)]) = o;
}

// LayerNorm in place over all 1024 rows (head LN, eps 1e-12). grid 1024.
__global__ __launch_bounds__(256) void k_ln_rows(
    float* __restrict__ buf, const float* __restrict__ g,
    const float* __restrict__ be, float eps)
{
    const int tid = threadIdx.x;
    float* rowp = buf + (size_t)blockIdx.x * Hh;
    float4 v = *reinterpret_cast<float4*>(&rowp[tid << 2]);
    float s1 = v.x + v.y + v.z + v.w;
    float s2 = v.x*v.x + v.y*v.y + v.z*v.z + v.w*v.w;
    #pragma unroll
    for (int off = 1; off < 64; off <<= 1) { s1 += __shfl_xor(s1, off); s2 += __shfl_xor(s2, off); }
    __shared__ float r1[4], r2[4];
    if ((tid & 63) == 0) { r1[tid >> 6] = s1; r2[tid >> 6] = s2; }
    __syncthreads();
    s1 = r1[0] + r1[1] + r1[2] + r1[3];
    s2 = r2[0] + r2[1] + r2[2] + r2[3];
    const float mu = s1 * (1.f / Hh);
    const float rs = rsqrtf(s2 * (1.f / Hh) - mu * mu + eps);
    const float4 g4 = *reinterpret_cast<const float4*>(&g[tid << 2]);
    const float4 b4 = *reinterpret_cast<const float4*>(&be[tid << 2]);
    float4 o;
    o.x = (v.x - mu) * rs * g4.x + b4.x;
    o.y = (v.y - mu) * rs * g4.y + b4.y;
    o.z = (v.z - mu) * rs * g4.z + b4.z;
    o.w = (v.w - mu) * rs * g4.w + b4.w;
    *reinterpret_cast<float4*>(&rowp[tid << 2]) = o;
}

// ---------------------------------------------------------------------------
// Decoder: C[1024][32000] = A[1024][1024] @ Wd[1024][32000] + bd.
// 64x64 tiles, block 256 (16x16 threads, 4x4 each, strided-by-16 cols/rows so
// the epilogue scalar stores (C is only 4B-aligned: d_out+1) stay coalesced.
// grid (500, 16).
// ---------------------------------------------------------------------------
__global__ __launch_bounds__(256) void k_decoder(
    const float* __restrict__ A, const float* __restrict__ Wd,
    const float* __restrict__ bd, float* __restrict__ C)
{
    __shared__ float As[16][68];
    __shared__ float Bs[16][68];
    const int tid = threadIdx.x;
    const int tx = tid & 15, ty = tid >> 4;
    const int n0 = blockIdx.x << 6, r0 = blockIdx.y << 6;
    float acc[4][4] = {};
    for (int k0 = 0; k0 < Hh; k0 += 16) {
        __syncthreads();
        #pragma unroll
        for (int u = 0; u < 4; ++u) {
            int e = (u << 8) + tid;
            int r = e >> 4, kk = e & 15;
            As[kk][r] = A[(size_t)(r0 + r) * Hh + k0 + kk];
        }
        #pragma unroll
        for (int u = 0; u < 4; ++u) {
            int e = (u << 8) + tid;
            int kk = e >> 6, nn = e & 63;
            Bs[kk][nn] = Wd[(size_t)(k0 + kk) * Vv + n0 + nn];
        }
        __syncthreads();
        #pragma unroll
        for (int kk = 0; kk < 16; ++kk) {
            float a[4], w[4];
            #pragma unroll
            for (int i = 0; i < 4; ++i) a[i] = As[kk][ty + (i << 4)];
            #pragma unroll
            for (int j = 0; j < 4; ++j) w[j] = Bs[kk][tx + (j << 4)];
            #pragma unroll
            for (int i = 0; i < 4; ++i)
                #pragma unroll
                for (int j = 0; j < 4; ++j)
                    acc[i][j] = fmaf(a[i], w[j], acc[i][j]);
        }
    }
    #pragma unroll
    for (int j = 0; j < 4; ++j) {
        const float bj = bd[n0 + tx + (j << 4)];
        #pragma unroll
        for (int i = 0; i < 4; ++i)
            C[(size_t)(r0 + ty + (i << 4)) * Vv + n0 + tx + (j << 4)] = acc[i][j] + bj;
    }
}

// ---------------------------------------------------------------------------
// CE loss: per-row online logsumexp, partial[row] = lse - logit[label].
// ---------------------------------------------------------------------------
__global__ __launch_bounds__(256) void k_loss_row(
    const float* __restrict__ logits, const int* __restrict__ labels,
    float* __restrict__ partial)
{
    const int row = blockIdx.x;
    const float* lr = logits + (size_t)row * Vv;
    float m = -3.4e38f, s = 0.f;
    for (int i = threadIdx.x; i < Vv; i += 256) {
        float v = lr[i];
        float nm = fmaxf(m, v);
        s = s * expf(m - nm) + expf(v - nm);
        m = nm;
    }
    #pragma unroll
    for (int off = 1; off < 64; off <<= 1) {
        float om = __shfl_xor(m, off);
        float os = __shfl_xor(s, off);
        float nm = fmaxf(m, om);
        s = s * expf(m - nm) + os * expf(om - nm);
        m = nm;
    }
    __shared__ float lm[4], ls[4];
    const int wid = threadIdx.x >> 6;
    if ((threadIdx.x & 63) == 0) { lm[wid] = m; ls[wid] = s; }
    __syncthreads();
    if (threadIdx.x == 0) {
        float M = lm[0], Sv = ls[0];
        #pragma unroll
        for (int w = 1; w < 4; ++w) {
            float nm = fmaxf(M, lm[w]);
            Sv = Sv * expf(M - nm) + ls[w] * expf(lm[w] - nm);
            M = nm;
        }
        partial[row] = (M + logf(Sv)) - lr[labels[row]];
    }
}

__global__ __launch_bounds__(256) void k_loss_final(
    const float* __restrict__ partial, float* __restrict__ out0)
{
    float s = partial[threadIdx.x] + partial[threadIdx.x + 256]
            + partial[threadIdx.x + 512] + partial[threadIdx.x + 768];
    #pragma unroll
    for (int off = 1; off < 64; off <<= 1) s += __shfl_xor(s, off);
    __shared__ float red[4];
    if ((threadIdx.x & 63) == 0) red[threadIdx.x >> 6] = s;
    __syncthreads();
    if (threadIdx.x == 0) out0[0] = (red[0] + red[1] + red[2] + red[3]) * (1.f / NROWS);
}

// ---------------------------------------------------------------------------
extern "C" void kernel_launch(void* const* d_in, const int* in_sizes, int n_in,
                              void* d_out, int out_size, void* d_ws, size_t ws_size,
                              hipStream_t stream)
{
    const int*   labels  = (const int*)d_in[0];
    const float* emb     = (const float*)d_in[1];
    const float* W_in    = (const float*)d_in[2];
    const float* b_in    = (const float*)d_in[3];
    const float* W_sani  = (const float*)d_in[4];
    const float* b_sani  = (const float*)d_in[5];
    const float* ln_g    = (const float*)d_in[6];
    const float* ln_b    = (const float*)d_in[7];
    const float* W_dense = (const float*)d_in[8];
    const float* b_dense = (const float*)d_in[9];
    const float* ln2_g   = (const float*)d_in[10];
    const float* ln2_b   = (const float*)d_in[11];
    const float* W_dec   = (const float*)d_in[12];
    const float* b_dec   = (const float*)d_in[13];
    float* out    = (float*)d_out;
    float* logits = out + 1;

    const size_t NH = (size_t)NROWS * Hh;   // 1M floats
    float* wsf = (float*)d_ws;
    float *h0, *h1, *os, *yb, *pt;
    if (ws_size >= (4 * NH + 1024) * sizeof(float)) {
        h0 = wsf; h1 = wsf + NH; os = wsf + 2 * NH; yb = wsf + 3 * NH; pt = wsf + 4 * NH;
    } else {
        // logits region is dead until k_decoder: borrow it (16B-aligned offset);
        // yb must survive into k_decoder, keep it (and partials) in ws.
        float* scratch = out + 8;
        h0 = scratch; h1 = scratch + NH; os = scratch + 2 * NH;
        yb = wsf; pt = wsf + NH;
    }

    hipMemsetAsync(os, 0, NH * sizeof(float), stream);  // rows 126/127 must be 0
    k_gemm1024<0><<<dim3(4, 64), 256, 0, stream>>>(labels, emb, W_in, b_in, h0);
    for (int m = 0; m < Ss - 2; ++m) {
        float* src = (m & 1) ? h1 : h0;
        float* dst = (m & 1) ? h0 : h1;
        int nt = Ss - 1 - m;
        k_scan_gemm<<<dim3(4, (nt + 15) / 16, Bb), 256, 0, stream>>>(src, W_sani, b_sani, dst, m);
        k_scan_ln<<<dim3(nt, Bb), 256, 0, stream>>>(dst, ln_g, ln_b, os, m);
    }
    k_gemm1024<1><<<dim3(4, 64), 256, 0, stream>>>(nullptr, os, W_dense, b_dense, yb);
    k_ln_rows<<<NROWS, 256, 0, stream>>>(yb, ln2_g, ln2_b, 1e-12f);
    k_decoder<<<dim3(Vv / 64, NROWS / 64), 256, 0, stream>>>(yb, W_dec, b_dec, logits);
    k_loss_row<<<NROWS, 256, 0, stream>>>(logits, labels, pt);
    k_loss_final<<<1, 256, 0, stream>>>(pt, out);
}

// Round 2
// 6619.391 us; speedup vs baseline: 3.2476x; 3.2476x over previous
//
#include <hip/hip_runtime.h>
#include <hip/hip_bf16.h>

#define Bb 8
#define Ss 128
#define Hh 1024
#define Ee 1024
#define Vv 32000
#define NROWS (Bb*Ss)   // 1024

typedef __bf16 bf16;
typedef __bf16 v8bf __attribute__((ext_vector_type(8)));
typedef __bf16 v4bf __attribute__((ext_vector_type(4)));
typedef float  f32x4 __attribute__((ext_vector_type(4)));

// ---------------------------------------------------------------------------
// Generic rows x 1024 GEMM, K=1024 (fp32, unchanged from round 1).
// MODE 0: A-row = emb[labels[row]] (gather), epilogue relu      (input proj)
// MODE 1: A-row = A[row]           (direct), epilogue exact gelu (head dense)
// ---------------------------------------------------------------------------
template<int MODE>
__global__ __launch_bounds__(256) void k_gemm1024(
    const int* __restrict__ labels, const float* __restrict__ A,
    const float* __restrict__ W, const float* __restrict__ bias,
    float* __restrict__ out)
{
    __shared__ float Als[16][32];
    const int tid  = threadIdx.x;
    const int jj   = (blockIdx.x << 8) + ((tid & 63) << 2);
    const int rg   = tid >> 6;
    const int row0 = blockIdx.y << 4;
    float acc[4][4] = {};
    for (int k0 = 0; k0 < Ee; k0 += 32) {
        __syncthreads();
        #pragma unroll
        for (int u = 0; u < 2; ++u) {
            int i = (u << 8) + tid;
            int r = i >> 5, kk = i & 31;
            int row = row0 + r;
            size_t base = (MODE == 0) ? (size_t)labels[row] * Ee : (size_t)row * Hh;
            Als[r][kk] = A[base + k0 + kk];
        }
        __syncthreads();
        #pragma unroll 8
        for (int kk = 0; kk < 32; ++kk) {
            const float4 w4 = *reinterpret_cast<const float4*>(&W[(size_t)(k0 + kk) * Hh + jj]);
            #pragma unroll
            for (int i = 0; i < 4; ++i) {
                float a = Als[(rg << 2) + i][kk];
                acc[i][0] = fmaf(a, w4.x, acc[i][0]);
                acc[i][1] = fmaf(a, w4.y, acc[i][1]);
                acc[i][2] = fmaf(a, w4.z, acc[i][2]);
                acc[i][3] = fmaf(a, w4.w, acc[i][3]);
            }
        }
    }
    const float4 b4 = *reinterpret_cast<const float4*>(&bias[jj]);
    #pragma unroll
    for (int i = 0; i < 4; ++i) {
        int row = row0 + (rg << 2) + i;
        float v[4] = {acc[i][0] + b4.x, acc[i][1] + b4.y, acc[i][2] + b4.z, acc[i][3] + b4.w};
        float o[4];
        #pragma unroll
        for (int j = 0; j < 4; ++j) {
            if (MODE == 0) o[j] = fmaxf(v[j], 0.f);
            else           o[j] = 0.5f * v[j] * (1.f + erff(v[j] * 0.70710678f));
        }
        *reinterpret_cast<float4*>(&out[(size_t)row * Hh + jj]) =
            make_float4(o[0], o[1], o[2], o[3]);
    }
}

// ---------------------------------------------------------------------------
// Pack W_sani [2048][1024] f32 -> fragment-linear bf16:
//   Wp[((c*64 + s)*64 + l)*8 + e] = W[32c + 8*(l>>4) + e][16s + (l&15)]
// so a GEMM B-stage is a coalesced 16B/lane load and LDS stays frag-linear.
// grid 64 (c), block 256.
// ---------------------------------------------------------------------------
__global__ __launch_bounds__(256) void k_pack_sani(
    const float* __restrict__ W, bf16* __restrict__ Wp)
{
    const int c  = blockIdx.x;
    const int l  = threadIdx.x & 63;
    const int sq = threadIdx.x >> 6;
    const int kb = (c << 5) + ((l >> 4) << 3);
    for (int p = 0; p < 16; ++p) {
        const int s = (p << 2) + sq;
        const int n = (s << 4) + (l & 15);
        v8bf pk;
        #pragma unroll
        for (int e = 0; e < 8; ++e)
            pk[e] = (bf16)W[(size_t)(kb + e) * Hh + n];
        *reinterpret_cast<v8bf*>(&Wp[(((size_t)c * 64 + s) * 64 + l) * 8]) = pk;
    }
}

// f32 -> bf16 bulk convert (h0 mirror). grid NROWS*Hh/1024, block 256.
__global__ __launch_bounds__(256) void k_f32_to_bf16(
    const float* __restrict__ src, bf16* __restrict__ dst)
{
    const size_t i = ((size_t)blockIdx.x * 256 + threadIdx.x) * 4;
    const float4 v = *reinterpret_cast<const float4*>(&src[i]);
    v4bf o; o[0] = (bf16)v.x; o[1] = (bf16)v.y; o[2] = (bf16)v.z; o[3] = (bf16)v.w;
    *reinterpret_cast<v4bf*>(&dst[i]) = o;
}

// ---------------------------------------------------------------------------
// Scan step m, MFMA bf16: rows t in [m+1,127]:
//   hfD[b,t,:] = 0.1*relu(hbA_window(t) @ W_sani + b_sani) + hfS[b,t,:]
// A window = contiguous 2048 bf16 at hbA[b, t-1, 0].
// Block: 64 t-rows x 128 n-cols, BK=32 double-buffered, 4 waves (2x2),
// wave tile 32x64 = 2x4 frags of 16x16x32. All LDS frag-linear (conflict-free).
// grid (8, ceil(nt/64), 8), block 256. LDS 24KB.
// ---------------------------------------------------------------------------
__global__ __launch_bounds__(256) void k_scan_mm(
    const bf16* __restrict__ hbA, const float* __restrict__ hfS,
    const bf16* __restrict__ Wp, const float* __restrict__ bias,
    float* __restrict__ hfD, int m)
{
    __shared__ __align__(16) char lds[24576];
    const int tid = threadIdx.x, l = tid & 63, w = tid >> 6;
    const int wm = w >> 1, wn = w & 1;
    const int n0 = blockIdx.x << 7;
    const int t0 = m + 1 + (blockIdx.y << 6);
    const int b  = blockIdx.z;
    const bf16*  hA = hbA + (size_t)b * Ss * Hh;
    const float* hS = hfS + (size_t)b * Ss * Hh;

    // staging sources: wave w stages A-sub w and B-subs 2w, 2w+1
    int tS = t0 + (w << 4) + (l & 15); if (tS > Ss - 1) tS = Ss - 1;
    const bf16* srcA = hA + (size_t)(tS - 1) * Hh + ((l >> 4) << 3);
    const bf16* pB0  = Wp + ((((size_t)blockIdx.x << 3) + (w << 1)) * 64 + l) * 8;
    const bf16* pB1  = pB0 + 64 * 8;                    // next n-sub
    // per-chunk strides: A += 32 elems, B += 64*64*8 elems

    const int aoff  = (w << 10) + (l << 4);
    const int boff0 = 4096 + ((w << 1) << 10) + (l << 4);
    const int boff1 = boff0 + 1024;

    uint4 ra, rb0, rb1;
    ra  = *reinterpret_cast<const uint4*>(srcA);
    rb0 = *reinterpret_cast<const uint4*>(pB0);
    rb1 = *reinterpret_cast<const uint4*>(pB1);
    *reinterpret_cast<uint4*>(&lds[aoff])  = ra;
    *reinterpret_cast<uint4*>(&lds[boff0]) = rb0;
    *reinterpret_cast<uint4*>(&lds[boff1]) = rb1;
    __syncthreads();

    f32x4 acc[2][4] = {};
    int cur = 0;
    for (int c = 0; c < 64; ++c) {
        if (c < 63) {
            ra  = *reinterpret_cast<const uint4*>(srcA + ((c + 1) << 5));
            rb0 = *reinterpret_cast<const uint4*>(pB0 + (size_t)(c + 1) * 32768);
            rb1 = *reinterpret_cast<const uint4*>(pB1 + (size_t)(c + 1) * 32768);
        }
        const int base = cur * 12288;
        v8bf af[2], bfr[4];
        #pragma unroll
        for (int mi = 0; mi < 2; ++mi)
            af[mi] = *reinterpret_cast<v8bf*>(&lds[base + (((wm << 1) + mi) << 10) + (l << 4)]);
        #pragma unroll
        for (int ni = 0; ni < 4; ++ni)
            bfr[ni] = *reinterpret_cast<v8bf*>(&lds[base + 4096 + (((wn << 2) + ni) << 10) + (l << 4)]);
        #pragma unroll
        for (int mi = 0; mi < 2; ++mi)
            #pragma unroll
            for (int ni = 0; ni < 4; ++ni)
                acc[mi][ni] = __builtin_amdgcn_mfma_f32_16x16x32_bf16(af[mi], bfr[ni], acc[mi][ni], 0, 0, 0);
        __syncthreads();
        if (c < 63) {
            cur ^= 1;
            const int nb = cur * 12288;
            *reinterpret_cast<uint4*>(&lds[nb + aoff])  = ra;
            *reinterpret_cast<uint4*>(&lds[nb + boff0]) = rb0;
            *reinterpret_cast<uint4*>(&lds[nb + boff1]) = rb1;
            __syncthreads();
        }
    }

    // epilogue: C/D map col=lane&15, row=4*(lane>>4)+j  [m89]
    const int r4 = (l >> 4) << 2;
    const int cn = l & 15;
    #pragma unroll
    for (int mi = 0; mi < 2; ++mi) {
        const int tb = t0 + (((wm << 1) + mi) << 4) + r4;
        #pragma unroll
        for (int ni = 0; ni < 4; ++ni) {
            const int n = n0 + (((wn << 2) + ni) << 4) + cn;
            const float bs = bias[n];
            #pragma unroll
            for (int j = 0; j < 4; ++j) {
                const int t = tb + j;
                if (t <= Ss - 1) {
                    hfD[((size_t)b * Ss + t) * Hh + n] =
                        0.1f * fmaxf(acc[mi][ni][j] + bs, 0.f) + hS[(size_t)t * Hh + n];
                }
            }
        }
    }
}

// ---------------------------------------------------------------------------
// Per-step LayerNorm (eps 1e-5) in place on hfD rows t in [m+1,127];
// writes bf16 mirror hbD; t==m+1 row -> outState[b, m, :] (f32).
// grid (nt, 8), block 256.
// ---------------------------------------------------------------------------
__global__ __launch_bounds__(256) void k_scan_ln2(
    float* __restrict__ hdst, const float* __restrict__ g,
    const float* __restrict__ be, bf16* __restrict__ hbD,
    float* __restrict__ outState, int m)
{
    const int t = m + 1 + blockIdx.x;
    const int b = blockIdx.y;
    const int tid = threadIdx.x;
    float* rowp = hdst + ((size_t)b * Ss + t) * Hh;
    float4 v = *reinterpret_cast<float4*>(&rowp[tid << 2]);
    float s1 = v.x + v.y + v.z + v.w;
    float s2 = v.x*v.x + v.y*v.y + v.z*v.z + v.w*v.w;
    #pragma unroll
    for (int off = 1; off < 64; off <<= 1) { s1 += __shfl_xor(s1, off); s2 += __shfl_xor(s2, off); }
    __shared__ float r1[4], r2[4];
    if ((tid & 63) == 0) { r1[tid >> 6] = s1; r2[tid >> 6] = s2; }
    __syncthreads();
    s1 = r1[0] + r1[1] + r1[2] + r1[3];
    s2 = r2[0] + r2[1] + r2[2] + r2[3];
    const float mu = s1 * (1.f / Hh);
    const float rs = rsqrtf(s2 * (1.f / Hh) - mu * mu + 1e-5f);
    const float4 g4 = *reinterpret_cast<const float4*>(&g[tid << 2]);
    const float4 b4 = *reinterpret_cast<const float4*>(&be[tid << 2]);
    float4 o;
    o.x = (v.x - mu) * rs * g4.x + b4.x;
    o.y = (v.y - mu) * rs * g4.y + b4.y;
    o.z = (v.z - mu) * rs * g4.z + b4.z;
    o.w = (v.w - mu) * rs * g4.w + b4.w;
    *reinterpret_cast<float4*>(&rowp[tid << 2]) = o;
    v4bf ob; ob[0] = (bf16)o.x; ob[1] = (bf16)o.y; ob[2] = (bf16)o.z; ob[3] = (bf16)o.w;
    *reinterpret_cast<v4bf*>(&hbD[((size_t)b * Ss + t) * Hh + (tid << 2)]) = ob;
    if (t == m + 1)
        *reinterpret_cast<float4*>(&outState[((size_t)b * Ss + m) * Hh + (tid << 2)]) = o;
}

// Head LayerNorm in place (eps 1e-12). grid 1024.
__global__ __launch_bounds__(256) void k_ln_rows(
    float* __restrict__ buf, const float* __restrict__ g,
    const float* __restrict__ be, float eps)
{
    const int tid = threadIdx.x;
    float* rowp = buf + (size_t)blockIdx.x * Hh;
    float4 v = *reinterpret_cast<float4*>(&rowp[tid << 2]);
    float s1 = v.x + v.y + v.z + v.w;
    float s2 = v.x*v.x + v.y*v.y + v.z*v.z + v.w*v.w;
    #pragma unroll
    for (int off = 1; off < 64; off <<= 1) { s1 += __shfl_xor(s1, off); s2 += __shfl_xor(s2, off); }
    __shared__ float r1[4], r2[4];
    if ((tid & 63) == 0) { r1[tid >> 6] = s1; r2[tid >> 6] = s2; }
    __syncthreads();
    s1 = r1[0] + r1[1] + r1[2] + r1[3];
    s2 = r2[0] + r2[1] + r2[2] + r2[3];
    const float mu = s1 * (1.f / Hh);
    const float rs = rsqrtf(s2 * (1.f / Hh) - mu * mu + eps);
    const float4 g4 = *reinterpret_cast<const float4*>(&g[tid << 2]);
    const float4 b4 = *reinterpret_cast<const float4*>(&be[tid << 2]);
    float4 o;
    o.x = (v.x - mu) * rs * g4.x + b4.x;
    o.y = (v.y - mu) * rs * g4.y + b4.y;
    o.z = (v.z - mu) * rs * g4.z + b4.z;
    o.w = (v.w - mu) * rs * g4.w + b4.w;
    *reinterpret_cast<float4*>(&rowp[tid << 2]) = o;
}

// ---------------------------------------------------------------------------
// Decoder fp32 (unchanged): C[1024][32000] = A @ Wd + bd. grid (500,16).
// ---------------------------------------------------------------------------
__global__ __launch_bounds__(256) void k_decoder(
    const float* __restrict__ A, const float* __restrict__ Wd,
    const float* __restrict__ bd, float* __restrict__ C)
{
    __shared__ float As[16][68];
    __shared__ float Bs[16][68];
    const int tid = threadIdx.x;
    const int tx = tid & 15, ty = tid >> 4;
    const int n0 = blockIdx.x << 6, r0 = blockIdx.y << 6;
    float acc[4][4] = {};
    for (int k0 = 0; k0 < Hh; k0 += 16) {
        __syncthreads();
        #pragma unroll
        for (int u = 0; u < 4; ++u) {
            int e = (u << 8) + tid;
            int r = e >> 4, kk = e & 15;
            As[kk][r] = A[(size_t)(r0 + r) * Hh + k0 + kk];
        }
        #pragma unroll
        for (int u = 0; u < 4; ++u) {
            int e = (u << 8) + tid;
            int kk = e >> 6, nn = e & 63;
            Bs[kk][nn] = Wd[(size_t)(k0 + kk) * Vv + n0 + nn];
        }
        __syncthreads();
        #pragma unroll
        for (int kk = 0; kk < 16; ++kk) {
            float a[4], wv[4];
            #pragma unroll
            for (int i = 0; i < 4; ++i) a[i] = As[kk][ty + (i << 4)];
            #pragma unroll
            for (int j = 0; j < 4; ++j) wv[j] = Bs[kk][tx + (j << 4)];
            #pragma unroll
            for (int i = 0; i < 4; ++i)
                #pragma unroll
                for (int j = 0; j < 4; ++j)
                    acc[i][j] = fmaf(a[i], wv[j], acc[i][j]);
        }
    }
    #pragma unroll
    for (int j = 0; j < 4; ++j) {
        const float bj = bd[n0 + tx + (j << 4)];
        #pragma unroll
        for (int i = 0; i < 4; ++i)
            C[(size_t)(r0 + ty + (i << 4)) * Vv + n0 + tx + (j << 4)] = acc[i][j] + bj;
    }
}

// ---------------------------------------------------------------------------
// CE loss (unchanged).
// ---------------------------------------------------------------------------
__global__ __launch_bounds__(256) void k_loss_row(
    const float* __restrict__ logits, const int* __restrict__ labels,
    float* __restrict__ partial)
{
    const int row = blockIdx.x;
    const float* lr = logits + (size_t)row * Vv;
    float m = -3.4e38f, s = 0.f;
    for (int i = threadIdx.x; i < Vv; i += 256) {
        float v = lr[i];
        float nm = fmaxf(m, v);
        s = s * expf(m - nm) + expf(v - nm);
        m = nm;
    }
    #pragma unroll
    for (int off = 1; off < 64; off <<= 1) {
        float om = __shfl_xor(m, off);
        float os = __shfl_xor(s, off);
        float nm = fmaxf(m, om);
        s = s * expf(m - nm) + os * expf(om - nm);
        m = nm;
    }
    __shared__ float lm[4], ls[4];
    const int wid = threadIdx.x >> 6;
    if ((threadIdx.x & 63) == 0) { lm[wid] = m; ls[wid] = s; }
    __syncthreads();
    if (threadIdx.x == 0) {
        float M = lm[0], Sv = ls[0];
        #pragma unroll
        for (int w = 1; w < 4; ++w) {
            float nm = fmaxf(M, lm[w]);
            Sv = Sv * expf(M - nm) + ls[w] * expf(lm[w] - nm);
            M = nm;
        }
        partial[row] = (M + logf(Sv)) - lr[labels[row]];
    }
}

__global__ __launch_bounds__(256) void k_loss_final(
    const float* __restrict__ partial, float* __restrict__ out0)
{
    float s = partial[threadIdx.x] + partial[threadIdx.x + 256]
            + partial[threadIdx.x + 512] + partial[threadIdx.x + 768];
    #pragma unroll
    for (int off = 1; off < 64; off <<= 1) s += __shfl_xor(s, off);
    __shared__ float red[4];
    if ((threadIdx.x & 63) == 0) red[threadIdx.x >> 6] = s;
    __syncthreads();
    if (threadIdx.x == 0) out0[0] = (red[0] + red[1] + red[2] + red[3]) * (1.f / NROWS);
}

// ---------------------------------------------------------------------------
extern "C" void kernel_launch(void* const* d_in, const int* in_sizes, int n_in,
                              void* d_out, int out_size, void* d_ws, size_t ws_size,
                              hipStream_t stream)
{
    const int*   labels  = (const int*)d_in[0];
    const float* emb     = (const float*)d_in[1];
    const float* W_in    = (const float*)d_in[2];
    const float* b_in    = (const float*)d_in[3];
    const float* W_sani  = (const float*)d_in[4];
    const float* b_sani  = (const float*)d_in[5];
    const float* ln_g    = (const float*)d_in[6];
    const float* ln_b    = (const float*)d_in[7];
    const float* W_dense = (const float*)d_in[8];
    const float* b_dense = (const float*)d_in[9];
    const float* ln2_g   = (const float*)d_in[10];
    const float* ln2_b   = (const float*)d_in[11];
    const float* W_dec   = (const float*)d_in[12];
    const float* b_dec   = (const float*)d_in[13];
    float* out    = (float*)d_out;
    float* logits = out + 1;

    const size_t NH = (size_t)NROWS * Hh;   // 1M elems
    float* wsf = (float*)d_ws;
    float *hf0, *hf1, *os, *yb, *pt;
    bf16 *hb0, *hb1, *Wp;
    if (ws_size >= 6 * NH * sizeof(float) + 8192) {
        hf0 = wsf; hf1 = wsf + NH; os = wsf + 2 * NH; yb = wsf + 3 * NH;
        Wp  = (bf16*)(wsf + 4 * NH);            // 2M bf16 = NH floats
        hb0 = (bf16*)(wsf + 5 * NH);            // 1M bf16
        hb1 = hb0 + NH;                         // 1M bf16
        pt  = (float*)(hb1 + NH);
    } else {
        // logits region (d_out+1..) is dead until k_decoder: carve scratch at
        // d_out+8 (16B aligned). Everything here dies before k_decoder writes.
        // yb is read BY k_decoder (must not alias logits) -> keep in ws.
        float* S = out + 8;
        hf0 = S; hf1 = S + NH; os = S + 2 * NH;
        Wp  = (bf16*)(S + 3 * NH);
        hb0 = (bf16*)(S + 4 * NH);
        hb1 = hb0 + NH;
        yb = wsf; pt = wsf + NH;
    }

    k_pack_sani<<<64, 256, 0, stream>>>(W_sani, Wp);
    hipMemsetAsync(os, 0, NH * sizeof(float), stream);  // rows 126/127 stay 0
    k_gemm1024<0><<<dim3(4, 64), 256, 0, stream>>>(labels, emb, W_in, b_in, hf0);
    k_f32_to_bf16<<<(int)(NH / 1024), 256, 0, stream>>>(hf0, hb0);

    for (int m = 0; m < Ss - 2; ++m) {
        const int src = m & 1;
        float* hfs = src ? hf1 : hf0;  float* hfd = src ? hf0 : hf1;
        bf16*  hbs = src ? hb1 : hb0;  bf16*  hbd = src ? hb0 : hb1;
        const int nt = Ss - 1 - m;
        k_scan_mm<<<dim3(8, (nt + 63) / 64, Bb), 256, 0, stream>>>(
            hbs, hfs, Wp, b_sani, hfd, m);
        k_scan_ln2<<<dim3(nt, Bb), 256, 0, stream>>>(hfd, ln_g, ln_b, hbd, os, m);
    }

    k_gemm1024<1><<<dim3(4, 64), 256, 0, stream>>>(nullptr, os, W_dense, b_dense, yb);
    k_ln_rows<<<NROWS, 256, 0, stream>>>(yb, ln2_g, ln2_b, 1e-12f);
    k_decoder<<<dim3(Vv / 64, NROWS / 64), 256, 0, stream>>>(yb, W_dec, b_dec, logits);
    k_loss_row<<<NROWS, 256, 0, stream>>>(logits, labels, pt);
    k_loss_final<<<1, 256, 0, stream>>>(pt, out);
}

// Round 3
// 4062.110 us; speedup vs baseline: 5.2921x; 1.6295x over previous
//
#include <hip/hip_runtime.h>
#include <hip/hip_bf16.h>

#define Bb 8
#define Ss 128
#define Hh 1024
#define Vv 32000
#define NROWS (Bb*Ss)   // 1024

typedef __bf16 bf16;
typedef __bf16 v8bf __attribute__((ext_vector_type(8)));
typedef __bf16 v4bf __attribute__((ext_vector_type(4)));
typedef float  f32x4 __attribute__((ext_vector_type(4)));

// ---------------------------------------------------------------------------
// Pack row-major f32 W[K][N] -> frag-linear bf16:
//   Wp[((c*(N/16) + s)*64 + l)*8 + e] = W[32c + 8*(l>>4) + e][16s + (l&15)]
// (identical layout to round-2's validated Wp). Coalesced float4 reads;
// scattered 2B writes merge in L2. block (c, sg): rows 32c..+31, cols sg*256..+255.
// ---------------------------------------------------------------------------
__global__ __launch_bounds__(256) void k_pack(
    const float* __restrict__ W, bf16* __restrict__ Wp, int N)
{
    const int c = blockIdx.x, n0 = blockIdx.y << 8;
    const int Ns = N >> 4;
    #pragma unroll
    for (int i = 0; i < 8; ++i) {
        int idx = (i << 8) + threadIdx.x;       // 0..2047 = 32 rows x 64 f4
        int kk = idx >> 6, nq = idx & 63;
        float4 v = *reinterpret_cast<const float4*>(
            &W[(size_t)((c << 5) + kk) * N + n0 + (nq << 2)]);
        float vv[4] = {v.x, v.y, v.z, v.w};
        #pragma unroll
        for (int d = 0; d < 4; ++d) {
            int n = n0 + (nq << 2) + d;
            int s = n >> 4;
            int l = (n & 15) + ((kk >> 3) << 4);
            int e = kk & 7;
            Wp[((((size_t)c * Ns + s) << 6) + (size_t)l) * 8 + e] = (bf16)vv[d];
        }
    }
}

// ---------------------------------------------------------------------------
// Generic rows x 1024 GEMM, K=1024 (fp32).
// MODE 0: A-row = emb[labels[row]] (gather), relu.  MODE 1: direct, exact gelu.
// ---------------------------------------------------------------------------
template<int MODE>
__global__ __launch_bounds__(256) void k_gemm1024(
    const int* __restrict__ labels, const float* __restrict__ A,
    const float* __restrict__ W, const float* __restrict__ bias,
    float* __restrict__ out)
{
    __shared__ float Als[16][32];
    const int tid  = threadIdx.x;
    const int jj   = (blockIdx.x << 8) + ((tid & 63) << 2);
    const int rg   = tid >> 6;
    const int row0 = blockIdx.y << 4;
    float acc[4][4] = {};
    for (int k0 = 0; k0 < Hh; k0 += 32) {
        __syncthreads();
        #pragma unroll
        for (int u = 0; u < 2; ++u) {
            int i = (u << 8) + tid;
            int r = i >> 5, kk = i & 31;
            int row = row0 + r;
            size_t base = (MODE == 0) ? (size_t)labels[row] * Hh : (size_t)row * Hh;
            Als[r][kk] = A[base + k0 + kk];
        }
        __syncthreads();
        #pragma unroll 8
        for (int kk = 0; kk < 32; ++kk) {
            const float4 w4 = *reinterpret_cast<const float4*>(&W[(size_t)(k0 + kk) * Hh + jj]);
            #pragma unroll
            for (int i = 0; i < 4; ++i) {
                float a = Als[(rg << 2) + i][kk];
                acc[i][0] = fmaf(a, w4.x, acc[i][0]);
                acc[i][1] = fmaf(a, w4.y, acc[i][1]);
                acc[i][2] = fmaf(a, w4.z, acc[i][2]);
                acc[i][3] = fmaf(a, w4.w, acc[i][3]);
            }
        }
    }
    const float4 b4 = *reinterpret_cast<const float4*>(&bias[jj]);
    #pragma unroll
    for (int i = 0; i < 4; ++i) {
        int row = row0 + (rg << 2) + i;
        float v[4] = {acc[i][0] + b4.x, acc[i][1] + b4.y, acc[i][2] + b4.z, acc[i][3] + b4.w};
        float o[4];
        #pragma unroll
        for (int j = 0; j < 4; ++j) {
            if (MODE == 0) o[j] = fmaxf(v[j], 0.f);
            else           o[j] = 0.5f * v[j] * (1.f + erff(v[j] * 0.70710678f));
        }
        *reinterpret_cast<float4*>(&out[(size_t)row * Hh + jj]) =
            make_float4(o[0], o[1], o[2], o[3]);
    }
}

// f32 -> bf16 bulk convert. grid NROWS*Hh/1024, block 256.
__global__ __launch_bounds__(256) void k_f32_to_bf16(
    const float* __restrict__ src, bf16* __restrict__ dst)
{
    const size_t i = ((size_t)blockIdx.x * 256 + threadIdx.x) * 4;
    const float4 v = *reinterpret_cast<const float4*>(&src[i]);
    v4bf o; o[0] = (bf16)v.x; o[1] = (bf16)v.y; o[2] = (bf16)v.z; o[3] = (bf16)v.w;
    *reinterpret_cast<v4bf*>(&dst[i]) = o;
}

// ---------------------------------------------------------------------------
// Scan step m (no-LDS, no-barrier MFMA): rows t in [m+1,127]:
//   hfD[b,t,:] = 0.1*relu(window(hbA)[t] @ W_sani + b_sani) + hfS[b,t,:]
// Block 32 t-rows x 64 cols; 4 waves (wm=w>>1, wn=w&1), wave tile 16x32.
// A-frags: per-lane gather from bf16 h (L1/L2-hit, one 64B line/row/chunk).
// B-frags: coalesced 16B/lane from frag-linear Wp (L2-resident, 4MB).
// grid (16, ceil(nt/32), 8), block 256.
// ---------------------------------------------------------------------------
__global__ __launch_bounds__(256) void k_scan_mm3(
    const bf16* __restrict__ hbA, const float* __restrict__ hfS,
    const bf16* __restrict__ Wp, const float* __restrict__ bias,
    float* __restrict__ hfD, int m)
{
    const int tid = threadIdx.x, l = tid & 63, w = tid >> 6;
    const int wm = w >> 1, wn = w & 1;
    const int n0 = blockIdx.x << 6;
    const int t0 = m + 1 + (blockIdx.y << 5);
    const int b  = blockIdx.z;

    int tA = t0 + (wm << 4) + (l & 15); if (tA > Ss - 1) tA = Ss - 1;
    const bf16* pA = hbA + (((size_t)(b * Ss + tA - 1)) << 10) + ((l >> 4) << 3);
    const int s0 = (blockIdx.x << 2) + (wn << 1);
    const bf16* pB0 = Wp + (((size_t)(s0 << 6) + l) << 3);
    const bf16* pB1 = pB0 + 512;   // next 16-col sub

    f32x4 acc[2] = {};
    #pragma unroll 4
    for (int c = 0; c < 64; ++c) {
        v8bf a  = *reinterpret_cast<const v8bf*>(pA + (c << 5));
        v8bf b0 = *reinterpret_cast<const v8bf*>(pB0 + ((size_t)c << 15));
        v8bf b1 = *reinterpret_cast<const v8bf*>(pB1 + ((size_t)c << 15));
        acc[0] = __builtin_amdgcn_mfma_f32_16x16x32_bf16(a, b0, acc[0], 0, 0, 0);
        acc[1] = __builtin_amdgcn_mfma_f32_16x16x32_bf16(a, b1, acc[1], 0, 0, 0);
    }

    // C/D map: col = l&15, row = 4*(l>>4)+j  [validated round 2]
    const int r4 = (l >> 4) << 2, cn = l & 15;
    #pragma unroll
    for (int ni = 0; ni < 2; ++ni) {
        const int n = n0 + (((wn << 1) + ni) << 4) + cn;
        const float bs = bias[n];
        #pragma unroll
        for (int j = 0; j < 4; ++j) {
            const int t = t0 + (wm << 4) + r4 + j;
            if (t <= Ss - 1) {
                const size_t off = (((size_t)(b * Ss + t)) << 10) + n;
                hfD[off] = 0.1f * fmaxf(acc[ni][j] + bs, 0.f) + hfS[off];
            }
        }
    }
}

// ---------------------------------------------------------------------------
// Per-step LayerNorm (eps 1e-5) in place on hfD rows; writes bf16 mirror hbD;
// t==m+1 row -> outState[b,m,:]. grid (nt, 8), block 256.
// ---------------------------------------------------------------------------
__global__ __launch_bounds__(256) void k_scan_ln2(
    float* __restrict__ hdst, const float* __restrict__ g,
    const float* __restrict__ be, bf16* __restrict__ hbD,
    float* __restrict__ outState, int m)
{
    const int t = m + 1 + blockIdx.x;
    const int b = blockIdx.y;
    const int tid = threadIdx.x;
    float* rowp = hdst + ((size_t)b * Ss + t) * Hh;
    float4 v = *reinterpret_cast<float4*>(&rowp[tid << 2]);
    float s1 = v.x + v.y + v.z + v.w;
    float s2 = v.x*v.x + v.y*v.y + v.z*v.z + v.w*v.w;
    #pragma unroll
    for (int off = 1; off < 64; off <<= 1) { s1 += __shfl_xor(s1, off); s2 += __shfl_xor(s2, off); }
    __shared__ float r1[4], r2[4];
    if ((tid & 63) == 0) { r1[tid >> 6] = s1; r2[tid >> 6] = s2; }
    __syncthreads();
    s1 = r1[0] + r1[1] + r1[2] + r1[3];
    s2 = r2[0] + r2[1] + r2[2] + r2[3];
    const float mu = s1 * (1.f / Hh);
    const float rs = rsqrtf(s2 * (1.f / Hh) - mu * mu + 1e-5f);
    const float4 g4 = *reinterpret_cast<const float4*>(&g[tid << 2]);
    const float4 b4 = *reinterpret_cast<const float4*>(&be[tid << 2]);
    float4 o;
    o.x = (v.x - mu) * rs * g4.x + b4.x;
    o.y = (v.y - mu) * rs * g4.y + b4.y;
    o.z = (v.z - mu) * rs * g4.z + b4.z;
    o.w = (v.w - mu) * rs * g4.w + b4.w;
    *reinterpret_cast<float4*>(&rowp[tid << 2]) = o;
    v4bf ob; ob[0] = (bf16)o.x; ob[1] = (bf16)o.y; ob[2] = (bf16)o.z; ob[3] = (bf16)o.w;
    *reinterpret_cast<v4bf*>(&hbD[((size_t)b * Ss + t) * Hh + (tid << 2)]) = ob;
    if (t == m + 1)
        *reinterpret_cast<float4*>(&outState[((size_t)b * Ss + m) * Hh + (tid << 2)]) = o;
}

// Head LayerNorm in place (eps 1e-12) + optional bf16 mirror. grid 1024.
__global__ __launch_bounds__(256) void k_ln_rows2(
    float* __restrict__ buf, const float* __restrict__ g,
    const float* __restrict__ be, bf16* __restrict__ ybb)
{
    const int tid = threadIdx.x;
    float* rowp = buf + (size_t)blockIdx.x * Hh;
    float4 v = *reinterpret_cast<float4*>(&rowp[tid << 2]);
    float s1 = v.x + v.y + v.z + v.w;
    float s2 = v.x*v.x + v.y*v.y + v.z*v.z + v.w*v.w;
    #pragma unroll
    for (int off = 1; off < 64; off <<= 1) { s1 += __shfl_xor(s1, off); s2 += __shfl_xor(s2, off); }
    __shared__ float r1[4], r2[4];
    if ((tid & 63) == 0) { r1[tid >> 6] = s1; r2[tid >> 6] = s2; }
    __syncthreads();
    s1 = r1[0] + r1[1] + r1[2] + r1[3];
    s2 = r2[0] + r2[1] + r2[2] + r2[3];
    const float mu = s1 * (1.f / Hh);
    const float rs = rsqrtf(s2 * (1.f / Hh) - mu * mu + 1e-12f);
    const float4 g4 = *reinterpret_cast<const float4*>(&g[tid << 2]);
    const float4 b4 = *reinterpret_cast<const float4*>(&be[tid << 2]);
    float4 o;
    o.x = (v.x - mu) * rs * g4.x + b4.x;
    o.y = (v.y - mu) * rs * g4.y + b4.y;
    o.z = (v.z - mu) * rs * g4.z + b4.z;
    o.w = (v.w - mu) * rs * g4.w + b4.w;
    *reinterpret_cast<float4*>(&rowp[tid << 2]) = o;
    if (ybb) {
        v4bf ob; ob[0] = (bf16)o.x; ob[1] = (bf16)o.y; ob[2] = (bf16)o.z; ob[3] = (bf16)o.w;
        *reinterpret_cast<v4bf*>(&ybb[(size_t)blockIdx.x * Hh + (tid << 2)]) = ob;
    }
}

// ---------------------------------------------------------------------------
// Decoder bf16 MFMA (fast path): C[1024][32000] = ybb @ Wdec + bd.
// Block 256 rows x 128 cols; 8 waves (wr=w>>1 0..3, wc=w&1), wave 64x64 = 4x4
// frags. No LDS, no barriers; wave-duplicate frag reads served by L1.
// grid (250, 4), block 512.
// ---------------------------------------------------------------------------
__global__ __launch_bounds__(512) void k_dec_mm(
    const bf16* __restrict__ A, const bf16* __restrict__ Wp,
    const float* __restrict__ bd, float* __restrict__ C)
{
    const int tid = threadIdx.x, l = tid & 63, w = tid >> 6;
    const int wr = w >> 1, wc = w & 1;
    const int n0 = (blockIdx.x << 7) + (wc << 6);
    const int r0 = (blockIdx.y << 8) + (wr << 6);
    const bf16* pA = A + (((size_t)(r0 + (l & 15))) << 10) + ((l >> 4) << 3);
    const int sb = (blockIdx.x << 3) + (wc << 2);
    const bf16* pB = Wp + (((size_t)(sb << 6) + l) << 3);

    f32x4 acc[4][4] = {};
    for (int c = 0; c < 32; ++c) {
        v8bf af[4], bfr[4];
        #pragma unroll
        for (int mi = 0; mi < 4; ++mi)
            af[mi] = *reinterpret_cast<const v8bf*>(pA + (((size_t)mi << 4) << 10) + (c << 5));
        #pragma unroll
        for (int ni = 0; ni < 4; ++ni)
            bfr[ni] = *reinterpret_cast<const v8bf*>(pB + (size_t)c * 1024000 + (ni << 9));
        #pragma unroll
        for (int mi = 0; mi < 4; ++mi)
            #pragma unroll
            for (int ni = 0; ni < 4; ++ni)
                acc[mi][ni] = __builtin_amdgcn_mfma_f32_16x16x32_bf16(af[mi], bfr[ni], acc[mi][ni], 0, 0, 0);
    }

    const int r4 = (l >> 4) << 2, cn = l & 15;
    #pragma unroll
    for (int mi = 0; mi < 4; ++mi) {
        #pragma unroll
        for (int ni = 0; ni < 4; ++ni) {
            const int col = n0 + (ni << 4) + cn;
            const float bj = bd[col];
            #pragma unroll
            for (int j = 0; j < 4; ++j) {
                const int row = r0 + (mi << 4) + r4 + j;
                C[(size_t)row * Vv + col] = acc[mi][ni][j] + bj;
            }
        }
    }
}

// ---------------------------------------------------------------------------
// Decoder fp32 (slow-path fallback, unchanged from round 2). grid (500,16).
// ---------------------------------------------------------------------------
__global__ __launch_bounds__(256) void k_decoder(
    const float* __restrict__ A, const float* __restrict__ Wd,
    const float* __restrict__ bd, float* __restrict__ C)
{
    __shared__ float As[16][68];
    __shared__ float Bs[16][68];
    const int tid = threadIdx.x;
    const int tx = tid & 15, ty = tid >> 4;
    const int n0 = blockIdx.x << 6, r0 = blockIdx.y << 6;
    float acc[4][4] = {};
    for (int k0 = 0; k0 < Hh; k0 += 16) {
        __syncthreads();
        #pragma unroll
        for (int u = 0; u < 4; ++u) {
            int e = (u << 8) + tid;
            int r = e >> 4, kk = e & 15;
            As[kk][r] = A[(size_t)(r0 + r) * Hh + k0 + kk];
        }
        #pragma unroll
        for (int u = 0; u < 4; ++u) {
            int e = (u << 8) + tid;
            int kk = e >> 6, nn = e & 63;
            Bs[kk][nn] = Wd[(size_t)(k0 + kk) * Vv + n0 + nn];
        }
        __syncthreads();
        #pragma unroll
        for (int kk = 0; kk < 16; ++kk) {
            float a[4], wv[4];
            #pragma unroll
            for (int i = 0; i < 4; ++i) a[i] = As[kk][ty + (i << 4)];
            #pragma unroll
            for (int j = 0; j < 4; ++j) wv[j] = Bs[kk][tx + (j << 4)];
            #pragma unroll
            for (int i = 0; i < 4; ++i)
                #pragma unroll
                for (int j = 0; j < 4; ++j)
                    acc[i][j] = fmaf(a[i], wv[j], acc[i][j]);
        }
    }
    #pragma unroll
    for (int j = 0; j < 4; ++j) {
        const float bj = bd[n0 + tx + (j << 4)];
        #pragma unroll
        for (int i = 0; i < 4; ++i)
            C[(size_t)(r0 + ty + (i << 4)) * Vv + n0 + tx + (j << 4)] = acc[i][j] + bj;
    }
}

// ---------------------------------------------------------------------------
// CE loss.
// ---------------------------------------------------------------------------
__global__ __launch_bounds__(256) void k_loss_row(
    const float* __restrict__ logits, const int* __restrict__ labels,
    float* __restrict__ partial)
{
    const int row = blockIdx.x;
    const float* lr = logits + (size_t)row * Vv;
    float m = -3.4e38f, s = 0.f;
    for (int i = threadIdx.x; i < Vv; i += 256) {
        float v = lr[i];
        float nm = fmaxf(m, v);
        s = s * expf(m - nm) + expf(v - nm);
        m = nm;
    }
    #pragma unroll
    for (int off = 1; off < 64; off <<= 1) {
        float om = __shfl_xor(m, off);
        float os = __shfl_xor(s, off);
        float nm = fmaxf(m, om);
        s = s * expf(m - nm) + os * expf(om - nm);
        m = nm;
    }
    __shared__ float lm[4], ls[4];
    const int wid = threadIdx.x >> 6;
    if ((threadIdx.x & 63) == 0) { lm[wid] = m; ls[wid] = s; }
    __syncthreads();
    if (threadIdx.x == 0) {
        float M = lm[0], Sv = ls[0];
        #pragma unroll
        for (int ww = 1; ww < 4; ++ww) {
            float nm = fmaxf(M, lm[ww]);
            Sv = Sv * expf(M - nm) + ls[ww] * expf(lm[ww] - nm);
            M = nm;
        }
        partial[row] = (M + logf(Sv)) - lr[labels[row]];
    }
}

__global__ __launch_bounds__(256) void k_loss_final(
    const float* __restrict__ partial, float* __restrict__ out0)
{
    float s = partial[threadIdx.x] + partial[threadIdx.x + 256]
            + partial[threadIdx.x + 512] + partial[threadIdx.x + 768];
    #pragma unroll
    for (int off = 1; off < 64; off <<= 1) s += __shfl_xor(s, off);
    __shared__ float red[4];
    if ((threadIdx.x & 63) == 0) red[threadIdx.x >> 6] = s;
    __syncthreads();
    if (threadIdx.x == 0) out0[0] = (red[0] + red[1] + red[2] + red[3]) * (1.f / NROWS);
}

// ---------------------------------------------------------------------------
extern "C" void kernel_launch(void* const* d_in, const int* in_sizes, int n_in,
                              void* d_out, int out_size, void* d_ws, size_t ws_size,
                              hipStream_t stream)
{
    const int*   labels  = (const int*)d_in[0];
    const float* emb     = (const float*)d_in[1];
    const float* W_in    = (const float*)d_in[2];
    const float* b_in    = (const float*)d_in[3];
    const float* W_sani  = (const float*)d_in[4];
    const float* b_sani  = (const float*)d_in[5];
    const float* ln_g    = (const float*)d_in[6];
    const float* ln_b    = (const float*)d_in[7];
    const float* W_dense = (const float*)d_in[8];
    const float* b_dense = (const float*)d_in[9];
    const float* ln2_g   = (const float*)d_in[10];
    const float* ln2_b   = (const float*)d_in[11];
    const float* W_dec   = (const float*)d_in[12];
    const float* b_dec   = (const float*)d_in[13];
    float* out    = (float*)d_out;
    float* logits = out + 1;

    const size_t NH = (size_t)NROWS * Hh;        // 1M elems
    const size_t WDP_ELEMS = (size_t)32 * 2000 * 64 * 8;  // 32.768M bf16

    // out-scratch: everything here is dead before k_dec_mm/k_decoder writes logits.
    float* S = out + 8;
    float* hf0 = S;
    float* hf1 = S + NH;
    float* os  = S + 2 * NH;
    bf16*  Wp  = (bf16*)(S + 3 * NH);            // 2M bf16 (sani packed)
    bf16*  hb0 = (bf16*)(S + 4 * NH);
    bf16*  hb1 = hb0 + NH;
    float* yb_fast = S + 5 * NH;

    const bool fast = ws_size >= WDP_ELEMS * 2 + NH * 2 + 8192;
    bf16 *Wdp = nullptr, *ybb = nullptr;
    float *yb, *pt;
    float* wsf = (float*)d_ws;
    if (fast) {
        Wdp = (bf16*)d_ws;
        ybb = Wdp + WDP_ELEMS;
        pt  = (float*)(ybb + NH);
        yb  = yb_fast;
    } else {
        yb = wsf;
        pt = wsf + NH;
    }

    k_pack<<<dim3(64, 4), 256, 0, stream>>>(W_sani, Wp, Hh);
    if (fast)
        k_pack<<<dim3(32, 125), 256, 0, stream>>>(W_dec, Wdp, Vv);

    hipMemsetAsync(os, 0, NH * sizeof(float), stream);   // rows 126/127 stay 0
    k_gemm1024<0><<<dim3(4, 64), 256, 0, stream>>>(labels, emb, W_in, b_in, hf0);
    k_f32_to_bf16<<<(int)(NH / 1024), 256, 0, stream>>>(hf0, hb0);

    for (int m = 0; m < Ss - 2; ++m) {
        const int src = m & 1;
        float* hfs = src ? hf1 : hf0;  float* hfd = src ? hf0 : hf1;
        bf16*  hbs = src ? hb1 : hb0;  bf16*  hbd = src ? hb0 : hb1;
        const int nt = Ss - 1 - m;
        k_scan_mm3<<<dim3(16, (nt + 31) / 32, Bb), 256, 0, stream>>>(
            hbs, hfs, Wp, b_sani, hfd, m);
        k_scan_ln2<<<dim3(nt, Bb), 256, 0, stream>>>(hfd, ln_g, ln_b, hbd, os, m);
    }

    k_gemm1024<1><<<dim3(4, 64), 256, 0, stream>>>(nullptr, os, W_dense, b_dense, yb);
    k_ln_rows2<<<NROWS, 256, 0, stream>>>(yb, ln2_g, ln2_b, ybb);
    if (fast)
        k_dec_mm<<<dim3(250, 4), 512, 0, stream>>>(ybb, Wdp, b_dec, logits);
    else
        k_decoder<<<dim3(Vv / 64, NROWS / 64), 256, 0, stream>>>(yb, W_dec, b_dec, logits);
    k_loss_row<<<NROWS, 256, 0, stream>>>(logits, labels, pt);
    k_loss_final<<<1, 256, 0, stream>>>(pt, out);
}